// Round 1
// baseline (920.152 us; speedup 1.0000x reference)
//
#include <hip/hip_runtime.h>

// ItemEncoder: out[t, j] = sum_k U[ids[t], k] * W[j, k] + b[j]
//   ids: int32 [12800], U: fp32 [100000, 2000], W: fp32 [8, 2000], b: fp32 [8]
// Memory-bound: 102.4 MB of gathered rows @ ~6.3 TB/s -> ~16.5 us floor.
//
// Strategy: one wave (64 lanes) per token. W staged in LDS padded to
// [8][2048] floats (64 KB exactly; pad zeroed so tail reads are safe).
// Each lane pulls 8 float4 of the row (whole 8 KB row in flight, coalesced),
// inner product against LDS W via conflict-free ds_read_b128, then a 6-step
// xor-butterfly reduction of the 8 accumulators.

#define IN_DIM   2000
#define IN_DIM4  500      // float4s per row
#define PAD_DIM4 512      // padded float4s per W row in LDS
#define OUT_DIM  8

__global__ __launch_bounds__(256, 2)
void item_encoder_kernel(const int* __restrict__ ids,
                         const float* __restrict__ U,
                         const float* __restrict__ W,
                         const float* __restrict__ bias,
                         float* __restrict__ out,
                         int T)
{
    __shared__ float4 wlds[OUT_DIM * PAD_DIM4];   // 64 KB -> 2 blocks/CU

    const int tid = threadIdx.x;

    // --- stage W into padded LDS (zero the pad) -------------------------
    const float4* Wv = (const float4*)W;          // [8 * 500]
    #pragma unroll
    for (int i = 0; i < 16; ++i) {
        int d  = tid + i * 256;                   // 0..4095
        int j  = d >> 9;                          // 0..7
        int k4 = d & 511;                         // 0..511
        float4 v = make_float4(0.f, 0.f, 0.f, 0.f);
        if (k4 < IN_DIM4) v = Wv[j * IN_DIM4 + k4];
        wlds[d] = v;
    }
    __syncthreads();

    const int lane    = tid & 63;
    const int wave    = tid >> 6;
    const int wave_id = blockIdx.x * 4 + wave;
    const int nwaves  = gridDim.x * 4;

    for (int t = wave_id; t < T; t += nwaves) {
        const int id = ids[t];
        const float4* row = (const float4*)(U + (size_t)id * IN_DIM);

        // pull the whole row: 8 coalesced dwordx4 per lane, all in flight
        float4 x[8];
        #pragma unroll
        for (int i = 0; i < 8; ++i) {
            const int k4 = lane + i * 64;         // 0..511
            x[i] = (k4 < IN_DIM4) ? row[k4] : make_float4(0.f, 0.f, 0.f, 0.f);
        }

        float acc[OUT_DIM];
        #pragma unroll
        for (int j = 0; j < OUT_DIM; ++j) acc[j] = 0.f;

        #pragma unroll
        for (int i = 0; i < 8; ++i) {
            const int k4 = lane + i * 64;
            const float4 xv = x[i];
            #pragma unroll
            for (int j = 0; j < OUT_DIM; ++j) {
                const float4 w = wlds[j * PAD_DIM4 + k4];
                acc[j] += xv.x * w.x + xv.y * w.y + xv.z * w.z + xv.w * w.w;
            }
        }

        // xor-butterfly reduce each acc[j] across the 64 lanes
        #pragma unroll
        for (int off = 32; off > 0; off >>= 1) {
            #pragma unroll
            for (int j = 0; j < OUT_DIM; ++j)
                acc[j] += __shfl_xor(acc[j], off, 64);
        }

        if (lane < OUT_DIM)
            out[(size_t)t * OUT_DIM + lane] = acc[lane] + bias[lane];
    }
}

extern "C" void kernel_launch(void* const* d_in, const int* in_sizes, int n_in,
                              void* d_out, int out_size, void* d_ws, size_t ws_size,
                              hipStream_t stream)
{
    const int*   ids  = (const int*)d_in[0];     // [B*L]
    const float* U    = (const float*)d_in[1];   // [NTOKEN, 2000]
    const float* W    = (const float*)d_in[2];   // [8, 2000]
    const float* bias = (const float*)d_in[3];   // [8]
    float*       out  = (float*)d_out;           // [B*L, 8]

    const int T = in_sizes[0];                   // 12800 tokens

    // 512 blocks x 256 thr: 2 blocks/CU (LDS-limited), 2048 waves,
    // ~6 tokens per wave via grid-stride.
    item_encoder_kernel<<<dim3(512), dim3(256), 0, stream>>>(ids, U, W, bias, out, T);
}

// Round 2
// 913.417 us; speedup vs baseline: 1.0074x; 1.0074x over previous
//
#include <hip/hip_runtime.h>

// ItemEncoder: out[t, j] = sum_k U[ids[t], k] * W[j, k] + b[j]
//   ids: int32 [12800], U: fp32 [100000, 2000], W: fp32 [8, 2000], b: fp32 [8]
// HBM-bound: 102.4 MB of gathered rows @ ~6.3 TB/s -> ~16.5 us kernel floor.
//
// One wave per token-PAIR: W staged once per block in LDS ([8][512] float4,
// 64 KB, pad zeroed -> 2 blocks/CU, conflict-free ds_read_b128). Each LDS
// read of W feeds FMAs for two tokens (halves LDS pipe traffic vs 1 token).
// Reduction: fold 8 accs -> 1 while butterflying (xor 1,2,4 with
// select-before-shuffle), then 3 octet butterflies = 10 shuffles/token
// (vs 48 naive). Final lane->j mapping is bit-reversed(lane&7).

#define IN_DIM   2000
#define IN_DIM4  500      // float4s per row
#define PAD_DIM4 512      // padded float4s per W row in LDS
#define OUT_DIM  8

__global__ __launch_bounds__(256, 2)
void item_encoder_kernel(const int* __restrict__ ids,
                         const float* __restrict__ U,
                         const float* __restrict__ W,
                         const float* __restrict__ bias,
                         float* __restrict__ out,
                         int T)
{
    __shared__ float4 wlds[OUT_DIM * PAD_DIM4];   // 64 KB

    const int tid = threadIdx.x;

    // --- stage W into padded LDS (zero the pad) -------------------------
    const float4* Wv = (const float4*)W;
    #pragma unroll
    for (int i = 0; i < 16; ++i) {
        int d  = tid + i * 256;
        int j  = d >> 9;
        int k4 = d & 511;
        float4 v = make_float4(0.f, 0.f, 0.f, 0.f);
        if (k4 < IN_DIM4) v = Wv[j * IN_DIM4 + k4];
        wlds[d] = v;
    }
    __syncthreads();

    const int lane    = tid & 63;
    const int wave    = tid >> 6;
    const int wave_id = blockIdx.x * 4 + wave;
    const int nwaves  = gridDim.x * 4;

    // j index this lane will own after the fold-reduce (bit-reversed low-3)
    const int jmap = ((lane & 1) << 2) | (lane & 2) | ((lane >> 2) & 1);
    const float bj = bias[jmap];   // 8-float vector, L1-resident broadcast

    for (int t0 = wave_id; t0 < T; t0 += 2 * nwaves) {
        const int t1   = t0 + nwaves;
        const bool has1 = (t1 < T);

        const int id0 = ids[t0];
        const int id1 = has1 ? ids[t1] : id0;
        const float4* r0 = (const float4*)(U + (size_t)id0 * IN_DIM);
        const float4* r1 = (const float4*)(U + (size_t)id1 * IN_DIM);

        // pull both rows: 16 coalesced dwordx4 per lane, all in flight
        float4 x0[8], x1[8];
        #pragma unroll
        for (int i = 0; i < 8; ++i) {
            const int  k4 = lane + i * 64;
            const bool in = (k4 < IN_DIM4);
            x0[i] = in ? r0[k4] : make_float4(0.f, 0.f, 0.f, 0.f);
            x1[i] = in ? r1[k4] : make_float4(0.f, 0.f, 0.f, 0.f);
        }

        float acc0[OUT_DIM], acc1[OUT_DIM];
        #pragma unroll
        for (int j = 0; j < OUT_DIM; ++j) { acc0[j] = 0.f; acc1[j] = 0.f; }

        // each W LDS read feeds BOTH tokens
        #pragma unroll
        for (int i = 0; i < 8; ++i) {
            const int k4 = lane + i * 64;
            const float4 a = x0[i];
            const float4 c = x1[i];
            #pragma unroll
            for (int j = 0; j < OUT_DIM; ++j) {
                const float4 w = wlds[j * PAD_DIM4 + k4];
                acc0[j] += a.x * w.x + a.y * w.y + a.z * w.z + a.w * w.w;
                acc1[j] += c.x * w.x + c.y * w.y + c.z * w.z + c.w * w.w;
            }
        }

        // ---- fold-reduce: 8 accs -> 1 value/lane (xor 1,2,4), then octets
        float v0, v1;
        {
            float a4[4], c4[4];
            #pragma unroll
            for (int m = 0; m < 4; ++m) {
                float sa = (lane & 1) ? acc0[m] : acc0[m + 4];
                float ka = (lane & 1) ? acc0[m + 4] : acc0[m];
                a4[m] = ka + __shfl_xor(sa, 1, 64);
                float sc = (lane & 1) ? acc1[m] : acc1[m + 4];
                float kc = (lane & 1) ? acc1[m + 4] : acc1[m];
                c4[m] = kc + __shfl_xor(sc, 1, 64);
            }
            float a2[2], c2[2];
            #pragma unroll
            for (int m = 0; m < 2; ++m) {
                float sa = (lane & 2) ? a4[m] : a4[m + 2];
                float ka = (lane & 2) ? a4[m + 2] : a4[m];
                a2[m] = ka + __shfl_xor(sa, 2, 64);
                float sc = (lane & 2) ? c4[m] : c4[m + 2];
                float kc = (lane & 2) ? c4[m + 2] : c4[m];
                c2[m] = kc + __shfl_xor(sc, 2, 64);
            }
            {
                float sa = (lane & 4) ? a2[0] : a2[1];
                float ka = (lane & 4) ? a2[1] : a2[0];
                v0 = ka + __shfl_xor(sa, 4, 64);
                float sc = (lane & 4) ? c2[0] : c2[1];
                float kc = (lane & 4) ? c2[1] : c2[0];
                v1 = kc + __shfl_xor(sc, 4, 64);
            }
            v0 += __shfl_xor(v0, 8, 64);  v1 += __shfl_xor(v1, 8, 64);
            v0 += __shfl_xor(v0, 16, 64); v1 += __shfl_xor(v1, 16, 64);
            v0 += __shfl_xor(v0, 32, 64); v1 += __shfl_xor(v1, 32, 64);
        }

        if (lane < OUT_DIM) {
            out[(size_t)t0 * OUT_DIM + jmap] = v0 + bj;
            if (has1)
                out[(size_t)t1 * OUT_DIM + jmap] = v1 + bj;
        }
    }
}

extern "C" void kernel_launch(void* const* d_in, const int* in_sizes, int n_in,
                              void* d_out, int out_size, void* d_ws, size_t ws_size,
                              hipStream_t stream)
{
    const int*   ids  = (const int*)d_in[0];     // [B*L]
    const float* U    = (const float*)d_in[1];   // [NTOKEN, 2000]
    const float* W    = (const float*)d_in[2];   // [8, 2000]
    const float* bias = (const float*)d_in[3];   // [8]
    float*       out  = (float*)d_out;           // [B*L, 8]

    const int T = in_sizes[0];                   // 12800 tokens

    // 512 blocks x 256 thr: 2 blocks/CU (LDS-limited), all co-resident,
    // 2048 waves, ~3 token-pairs per wave.
    item_encoder_kernel<<<dim3(512), dim3(256), 0, stream>>>(ids, U, W, bias, out, T);
}